// Round 3
// baseline (75.124 us; speedup 1.0000x reference)
//
#include <hip/hip_runtime.h>

// Quantum state-vector simulation: out[b] = Re( M[b>>2] @ input[b] ).
// Qubit q <-> amp bit (9-q). Entangler == Gray permute: state'[x^(x>>1)] = state[x].
//
// R9 (this round): occupancy fix. R8 ran 128 blocks x 256 thr = 1 wave/SIMD
// (minimum occupancy; ~85% stall: 3.2us issue vs ~20us measured). Now
// 64 blocks x 512 threads: TWO independent vectors per block (half h = tid>>8),
// each half identical to the verified R8 256-thread kernel (tid0 = tid&255),
// own stA/stB buffers, shared gate table (same params copy for both halves).
// -> 2 waves/SIMD, dependency/shuffle/exchange latency hidden by TLP.
// All R5-R8 verified indexing (masks, SWZ, Gray constants, output) unchanged.
// OUTPUT: out_size==131072 -> f32 real part; 262144 -> bf16 fallback.

#define DIM 1024
#define NQ 10
#define NLAYERS 8
#define NGATES 80

// slot-index (float4 units) bank swizzle for the exchange buffers (R7-verified):
// flips pair order by k-bit2 so 16B starts cycle over all 8 bank offsets.
#define SWZ(j) ((j) ^ (((j) >> 3) & 1))

__device__ __forceinline__ unsigned short f2bf(float f) {
    unsigned int u = __float_as_uint(f);
    unsigned int r = u + 0x7FFFu + ((u >> 16) & 1u);
    return (unsigned short)(r >> 16);
}

// c0*x0 + c1*x1, complex
__device__ __forceinline__ float2 cmadd2(float2 c0, float2 x0, float2 c1, float2 x1) {
    float re = c0.x * x0.x - c0.y * x0.y + c1.x * x1.x - c1.y * x1.y;
    float im = c0.x * x0.y + c0.y * x0.x + c1.x * x1.y + c1.y * x1.x;
    return make_float2(re, im);
}

// value of this register from lane^(1<<M), within a 64-lane wave.
// M=0,1: DPP quad_perm (xor1 = 0xB1; xor2 = 0x4E)          [R7 HW-verified]
// M=3:   DPP row_ror:8 (== xor 8 within a 16-row)          [R7 HW-verified]
// M=2:   ds_swizzle bitmode xor-4 (0x101F)                 [R6/R7 HW-verified]
// M=4:   permlane16_swap: hi ? res0 : res1                 [R8 HW-verified]
// M=5:   permlane32_swap: hi ? res0 : res1                 [R8 HW-verified]
template <int M>
__device__ __forceinline__ float lxor(float v, bool hi) {
    if constexpr (M == 0)
        return __int_as_float(__builtin_amdgcn_update_dpp(0, __float_as_int(v), 0xB1, 0xF, 0xF, true));
    else if constexpr (M == 1)
        return __int_as_float(__builtin_amdgcn_update_dpp(0, __float_as_int(v), 0x4E, 0xF, 0xF, true));
    else if constexpr (M == 3)
        return __int_as_float(__builtin_amdgcn_update_dpp(0, __float_as_int(v), 0x128, 0xF, 0xF, true));
    else if constexpr (M == 2)
        return __int_as_float(__builtin_amdgcn_ds_swizzle(__float_as_int(v), 0x101F));
    else if constexpr (M == 4) {
#if __has_builtin(__builtin_amdgcn_permlane16_swap)
        auto r = __builtin_amdgcn_permlane16_swap(__float_as_uint(v), __float_as_uint(v), false, false);
        return __uint_as_float(hi ? r[0] : r[1]);
#else
        return __int_as_float(__builtin_amdgcn_ds_swizzle(__float_as_int(v), 0x401F));
#endif
    } else {
#if __has_builtin(__builtin_amdgcn_permlane32_swap)
        auto r = __builtin_amdgcn_permlane32_swap(__float_as_uint(v), __float_as_uint(v), false, false);
        return __uint_as_float(hi ? r[0] : r[1]);
#else
        return __shfl_xor(v, 32, 64);
#endif
    }
}

// Gate stored as (m11.re, m11.im, m12.re, m12.im); unitary structure gives
// m21 = (-m12.x, m12.y), m22 = (m11.x, -m11.y)  [R7-verified].

template <int K>  // amp bit K in {0,1}: register-local pairs within a[4]
__device__ __forceinline__ void local_gate(float2 (&a)[4], float2 m11, float2 m12) {
    const float2 m21 = make_float2(-m12.x, m12.y);
    const float2 m22 = make_float2(m11.x, -m11.y);
#pragma unroll
    for (int p = 0; p < 2; ++p) {
        const int i0 = ((p >> K) << (K + 1)) | (p & ((1 << K) - 1));
        const int i1 = i0 | (1 << K);
        const float2 a0 = a[i0], a1 = a[i1];
        a[i0] = cmadd2(m11, a0, m12, a1);
        a[i1] = cmadd2(m21, a0, m22, a1);
    }
}

template <int M>  // lane bit M in [0,5] == amp bit M+2 (verified on HW in R5)
__device__ __forceinline__ void cross_gate(float2 (&a)[4], int lane, float2 m11, float2 m12) {
    const bool hi = (lane >> M) & 1;
    // cs = hi ? m22 : m11 ; co = hi ? m21 : m12  (conjugate-derived)
    const float2 cs = make_float2(m11.x, hi ? -m11.y : m11.y);
    const float2 co = make_float2(hi ? -m12.x : m12.x, m12.y);
#pragma unroll
    for (int r = 0; r < 4; ++r) {
        float2 o;
        o.x = lxor<M>(a[r].x, hi);
        o.y = lxor<M>(a[r].y, hi);
        a[r] = cmadd2(cs, a[r], co, o);
    }
}

__global__ __launch_bounds__(512) void
UnitaryR3Ansatz_18846316495450_kernel(const float* __restrict__ inp,     // [128][1024] f32
                                      const float* __restrict__ params,  // [32][8][10][3] f32
                                      void* __restrict__ outp,
                                      int out_size)
{
    __shared__ float4 gates[NGATES];        // (m11.re, m11.im, m12.re, m12.im)
    __shared__ float4 stA[2][DIM / 2];      // per-half state buffers
    __shared__ float4 stB[2][DIM / 2];

    const int tid  = threadIdx.x;        // 0..511
    const int h    = tid >> 8;           // half: which of the block's 2 vectors
    const int tid0 = tid & 255;          // amp bits 2-9 within the half
    const int b    = blockIdx.x * 2 + h; // vector 0..127
    const int c    = b >> 2;             // params copy (== blockIdx.x>>1, same for both halves)
    const int lane = tid & 63;           // amp bits 2-7 (bit 8 of tid doesn't touch it)

    if (tid < NGATES) {
        const float* p = params + c * (NGATES * 3) + tid * 3;
        const float omega = p[0], theta = p[1], phi = p[2];
        float sh, ch;  sincosf(0.5f * theta, &sh, &ch);
        float sa, ca;  sincosf(0.5f * (phi + omega), &sa, &ca);
        float sb, cb;  sincosf(0.5f * (phi - omega), &sb, &cb);
        gates[tid] = make_float4(ca * ch, -sa * ch, -cb * sh, -sb * sh);  // m11, m12
    }

    float2 a[4];
    {
        const float4 v = ((const float4*)(inp + b * DIM))[tid0];
        a[0] = make_float2(v.x, 0.f);
        a[1] = make_float2(v.y, 0.f);
        a[2] = make_float2(v.z, 0.f);
        a[3] = make_float2(v.w, 0.f);
    }

    // ---- exchange constants: y = my output amp = tid0*4 + r; z = invgray10(y) ----
    const int xb = tid0 << 2;
    int zb = xb;
    zb ^= zb >> 1; zb ^= zb >> 2; zb ^= zb >> 4; zb ^= zb >> 8;  // invgray of (y with r=0)
    const int  zmid = zb & 0xFC;        // z bits 2-7 (constant over r)
    const int  j0 = zmid >> 1;          // even float4 slot of cluster base
    const bool z8 = (zb >> 8) & 1;      // z bit 8 (constant over r)
    const bool z9 = (zb >> 9) & 1;      // z bit 9
    const bool s0 = zb & 1;             // z low-2 offset: zlow2(r) = (zb ^ gray2(r)) & 3
    const bool s1 = zb & 2;

    __syncthreads();

    float4* buf = stA[h];
    for (int l = 0; l < NLAYERS; ++l) {
        float2 m11, m12;
#define LOADG(q) { const float4 g = gates[l * NQ + (q)]; \
                   m11 = make_float2(g.x, g.y); m12 = make_float2(g.z, g.w); }
        // rotation gates commute (disjoint qubits): apply cheap->expensive
        LOADG(9); local_gate<0>(a, m11, m12);             // qubit 9 -> bit 0
        LOADG(8); local_gate<1>(a, m11, m12);             // qubit 8 -> bit 1
        LOADG(7); cross_gate<0>(a, lane, m11, m12);       // bit 2 (DPP)
        LOADG(6); cross_gate<1>(a, lane, m11, m12);       // bit 3 (DPP)
        LOADG(5); cross_gate<2>(a, lane, m11, m12);       // bit 4 (ds_swizzle)
        LOADG(4); cross_gate<3>(a, lane, m11, m12);       // bit 5 (DPP)
        LOADG(3); cross_gate<4>(a, lane, m11, m12);       // bit 6 (permlane16_swap)
        LOADG(2); cross_gate<5>(a, lane, m11, m12);       // bit 7 (permlane32_swap)

        // ---- LDS exchange: gates on bits 8,9 (qubits 1,0) + Gray permute ----
        buf[SWZ(tid0 * 2)]     = make_float4(a[0].x, a[0].y, a[1].x, a[1].y);
        buf[SWZ(tid0 * 2 + 1)] = make_float4(a[2].x, a[2].y, a[3].x, a[3].y);
        __syncthreads();

        LOADG(1);  // qubit 1 -> bit 8; row select by my output z8
        const float2 h0 = z8 ? make_float2(-m12.x, m12.y) : m11;   // z8 ? m21 : m11
        const float2 h1 = z8 ? make_float2(m11.x, -m11.y) : m12;   // z8 ? m22 : m12
        LOADG(0);  // qubit 0 -> bit 9; row select by z9
        const float2 g0r = z9 ? make_float2(-m12.x, m12.y) : m11;
        const float2 g1r = z9 ? make_float2(m11.x, -m11.y) : m12;
#undef LOADG

        // read clusters s[b9][b8][zmid][slot 0..3] and contract over b8 then b9
        float2 v0[4], v1[4];
        {   // b9 = 0
            const float4 p0 = buf[SWZ(j0)],         p1 = buf[SWZ(j0 + 1)];
            const float4 q0 = buf[SWZ(j0 + 0x80)],  q1 = buf[SWZ(j0 + 0x81)];
            v0[0] = cmadd2(h0, make_float2(p0.x, p0.y), h1, make_float2(q0.x, q0.y));
            v0[1] = cmadd2(h0, make_float2(p0.z, p0.w), h1, make_float2(q0.z, q0.w));
            v0[2] = cmadd2(h0, make_float2(p1.x, p1.y), h1, make_float2(q1.x, q1.y));
            v0[3] = cmadd2(h0, make_float2(p1.z, p1.w), h1, make_float2(q1.z, q1.w));
        }
        {   // b9 = 1
            const float4 p0 = buf[SWZ(j0 + 0x100)], p1 = buf[SWZ(j0 + 0x101)];
            const float4 q0 = buf[SWZ(j0 + 0x180)], q1 = buf[SWZ(j0 + 0x181)];
            v1[0] = cmadd2(h0, make_float2(p0.x, p0.y), h1, make_float2(q0.x, q0.y));
            v1[1] = cmadd2(h0, make_float2(p0.z, p0.w), h1, make_float2(q0.z, q0.w));
            v1[2] = cmadd2(h0, make_float2(p1.x, p1.y), h1, make_float2(q1.x, q1.y));
            v1[3] = cmadd2(h0, make_float2(p1.z, p1.w), h1, make_float2(q1.z, q1.w));
        }
        float2 u[4];
#pragma unroll
        for (int j = 0; j < 4; ++j) u[j] = cmadd2(g0r, v0[j], g1r, v1[j]);

        // a[r] = u[(zb ^ gray2(r)) & 3]: XOR-permute by zb&3, then static gray map
        const float2 w0 = s0 ? u[1] : u[0];
        const float2 w1 = s0 ? u[0] : u[1];
        const float2 w2 = s0 ? u[3] : u[2];
        const float2 w3 = s0 ? u[2] : u[3];
        a[0] = s1 ? w2 : w0;   // u2[0]
        a[1] = s1 ? w3 : w1;   // u2[1]
        a[2] = s1 ? w1 : w3;   // u2[3]  (gray2(2)=3)
        a[3] = s1 ? w0 : w2;   // u2[2]  (gray2(3)=2)

        buf = (l & 1) ? stA[h] : stB[h];   // double buffer per half
    }

    if (out_size >= 2 * DIM * 128) {
        // bf16 (re,im) interleaved, packed into one 16B store
        uint4 o;
        o.x = ((unsigned)f2bf(a[0].y) << 16) | f2bf(a[0].x);
        o.y = ((unsigned)f2bf(a[1].y) << 16) | f2bf(a[1].x);
        o.z = ((unsigned)f2bf(a[2].y) << 16) | f2bf(a[2].x);
        o.w = ((unsigned)f2bf(a[3].y) << 16) | f2bf(a[3].x);
        *reinterpret_cast<uint4*>((ushort2*)outp + (size_t)b * DIM + tid0 * 4) = o;
    } else {
        // float32 real part (verified layout)
        ((float4*)((float*)outp + (size_t)b * DIM))[tid0] =
            make_float4(a[0].x, a[1].x, a[2].x, a[3].x);
    }
}

extern "C" void kernel_launch(void* const* d_in, const int* in_sizes, int n_in,
                              void* d_out, int out_size, void* d_ws, size_t ws_size,
                              hipStream_t stream) {
    const float* inp    = (const float*)d_in[0];   // 131072 f32
    const float* params = (const float*)d_in[1];   // 7680 f32
    (void)in_sizes; (void)n_in; (void)d_ws; (void)ws_size;
    UnitaryR3Ansatz_18846316495450_kernel<<<64, 512, 0, stream>>>(inp, params, d_out, out_size);
}

// Round 4
// 66.764 us; speedup vs baseline: 1.1252x; 1.1252x over previous
//
#include <hip/hip_runtime.h>

// Quantum state-vector simulation: out[b] = Re( M[b>>2] @ input[b] ).
// Qubit q <-> amp bit (9-q). Entangler == Gray permute: state'[x^(x>>1)] = state[x].
//
// R10: revert to the verified R8 config (128 blocks x 256 threads, 1 vec/block
// -- R9's 2-vec/block halved CU count and regressed +8.3us) and cut VALU issue:
// all complex math rewritten on ext_vector float2 with __builtin_elementwise_fma
// so LLVM emits v_pk_fma_f32/v_pk_mul_f32 (VOP3P, 2 f32/slot, swap-neg folded
// into op_sel/neg modifiers). cmadd2: 8 scalar FMA -> 4 packed slots.
// Masks/SWZ/Gray/exchange indexing byte-identical to R8 (HW-verified R5-R8).
// OUTPUT: out_size==131072 -> f32 real part; 262144 -> bf16 fallback.

#define DIM 1024
#define NQ 10
#define NLAYERS 8
#define NGATES 80

typedef float v2f __attribute__((ext_vector_type(2)));

// slot-index (float4 units) bank swizzle for the exchange buffers (R7-verified):
// flips pair order by k-bit2 so 16B starts cycle over all 8 bank offsets.
#define SWZ(j) ((j) ^ (((j) >> 3) & 1))

__device__ __forceinline__ unsigned short f2bf(float f) {
    unsigned int u = __float_as_uint(f);
    unsigned int r = u + 0x7FFFu + ((u >> 16) & 1u);
    return (unsigned short)(r >> 16);
}

// acc-style complex mul-adds on packed [re, im] pairs.
// c*x = [c.x,c.x]*x + [c.y,c.y]*[-x.y, x.x]  -> pk_mul/pk_fma with op_sel+neg.
__device__ __forceinline__ v2f cmadd2(v2f c0, v2f x0, v2f c1, v2f x1) {
    v2f r = (v2f){c0.x, c0.x} * x0;
    r = __builtin_elementwise_fma((v2f){c0.y, c0.y}, (v2f){-x0.y, x0.x}, r);
    r = __builtin_elementwise_fma((v2f){c1.x, c1.x}, x1, r);
    r = __builtin_elementwise_fma((v2f){c1.y, c1.y}, (v2f){-x1.y, x1.x}, r);
    return r;
}

// value of this register from lane^(1<<M), within a 64-lane wave.
// M=0,1: DPP quad_perm (xor1 = 0xB1; xor2 = 0x4E)          [R7 HW-verified]
// M=3:   DPP row_ror:8 (== xor 8 within a 16-row)          [R7 HW-verified]
// M=2:   ds_swizzle bitmode xor-4 (0x101F)                 [R6/R7 HW-verified]
// M=4:   permlane16_swap: hi ? res0 : res1                 [R8 HW-verified]
// M=5:   permlane32_swap: hi ? res0 : res1                 [R8 HW-verified]
template <int M>
__device__ __forceinline__ float lxor(float v, bool hi) {
    if constexpr (M == 0)
        return __int_as_float(__builtin_amdgcn_update_dpp(0, __float_as_int(v), 0xB1, 0xF, 0xF, true));
    else if constexpr (M == 1)
        return __int_as_float(__builtin_amdgcn_update_dpp(0, __float_as_int(v), 0x4E, 0xF, 0xF, true));
    else if constexpr (M == 3)
        return __int_as_float(__builtin_amdgcn_update_dpp(0, __float_as_int(v), 0x128, 0xF, 0xF, true));
    else if constexpr (M == 2)
        return __int_as_float(__builtin_amdgcn_ds_swizzle(__float_as_int(v), 0x101F));
    else if constexpr (M == 4) {
#if __has_builtin(__builtin_amdgcn_permlane16_swap)
        auto r = __builtin_amdgcn_permlane16_swap(__float_as_uint(v), __float_as_uint(v), false, false);
        return __uint_as_float(hi ? r[0] : r[1]);
#else
        return __int_as_float(__builtin_amdgcn_ds_swizzle(__float_as_int(v), 0x401F));
#endif
    } else {
#if __has_builtin(__builtin_amdgcn_permlane32_swap)
        auto r = __builtin_amdgcn_permlane32_swap(__float_as_uint(v), __float_as_uint(v), false, false);
        return __uint_as_float(hi ? r[0] : r[1]);
#else
        return __shfl_xor(v, 32, 64);
#endif
    }
}

// Gate stored as (m11.re, m11.im, m12.re, m12.im); unitary structure gives
// m21 = (-m12.x, m12.y), m22 = (m11.x, -m11.y)  [R7-verified].

template <int K>  // amp bit K in {0,1}: register-local pairs within a[4]
__device__ __forceinline__ void local_gate(v2f (&a)[4], v2f m11, v2f m12) {
    const v2f m21 = (v2f){-m12.x, m12.y};
    const v2f m22 = (v2f){m11.x, -m11.y};
#pragma unroll
    for (int p = 0; p < 2; ++p) {
        const int i0 = ((p >> K) << (K + 1)) | (p & ((1 << K) - 1));
        const int i1 = i0 | (1 << K);
        const v2f a0 = a[i0], a1 = a[i1];
        a[i0] = cmadd2(m11, a0, m12, a1);
        a[i1] = cmadd2(m21, a0, m22, a1);
    }
}

template <int M>  // lane bit M in [0,5] == amp bit M+2 (verified on HW in R5)
__device__ __forceinline__ void cross_gate(v2f (&a)[4], int lane, v2f m11, v2f m12) {
    const bool hi = (lane >> M) & 1;
    // cs = hi ? m22 : m11 ; co = hi ? m21 : m12  (conjugate-derived)
    const v2f cs = (v2f){m11.x, hi ? -m11.y : m11.y};
    const v2f co = (v2f){hi ? -m12.x : m12.x, m12.y};
#pragma unroll
    for (int r = 0; r < 4; ++r) {
        v2f o;
        o.x = lxor<M>(a[r].x, hi);
        o.y = lxor<M>(a[r].y, hi);
        a[r] = cmadd2(cs, a[r], co, o);
    }
}

__global__ __launch_bounds__(256) void
UnitaryR3Ansatz_18846316495450_kernel(const float* __restrict__ inp,     // [128][1024] f32
                                      const float* __restrict__ params,  // [32][8][10][3] f32
                                      void* __restrict__ outp,
                                      int out_size)
{
    __shared__ float4 gates[NGATES];      // (m11.re, m11.im, m12.re, m12.im)
    __shared__ float4 stA[DIM / 2];       // state buffers, float2[1024] viewed as float4
    __shared__ float4 stB[DIM / 2];

    const int b = blockIdx.x;        // vector 0..127
    const int c = b >> 2;            // params copy
    const int tid = threadIdx.x;     // 0..255 == amp bits 2-9
    const int lane = tid & 63;       // amp bits 2-7

    if (tid < NGATES) {
        const float* p = params + c * (NGATES * 3) + tid * 3;
        const float omega = p[0], theta = p[1], phi = p[2];
        float sh, ch;  sincosf(0.5f * theta, &sh, &ch);
        float sa, ca;  sincosf(0.5f * (phi + omega), &sa, &ca);
        float sb, cb;  sincosf(0.5f * (phi - omega), &sb, &cb);
        gates[tid] = make_float4(ca * ch, -sa * ch, -cb * sh, -sb * sh);  // m11, m12
    }

    v2f a[4];
    {
        const float4 v = ((const float4*)(inp + b * DIM))[tid];
        a[0] = (v2f){v.x, 0.f};
        a[1] = (v2f){v.y, 0.f};
        a[2] = (v2f){v.z, 0.f};
        a[3] = (v2f){v.w, 0.f};
    }

    // ---- exchange constants: y = my output amp = tid*4 + r; z = invgray10(y) ----
    const int xb = tid << 2;
    int zb = xb;
    zb ^= zb >> 1; zb ^= zb >> 2; zb ^= zb >> 4; zb ^= zb >> 8;  // invgray of (y with r=0)
    const int  zmid = zb & 0xFC;        // z bits 2-7 (constant over r)
    const int  j0 = zmid >> 1;          // even float4 slot of cluster base
    const bool z8 = (zb >> 8) & 1;      // z bit 8 (constant over r)
    const bool z9 = (zb >> 9) & 1;      // z bit 9
    const bool s0 = zb & 1;             // z low-2 offset: zlow2(r) = (zb ^ gray2(r)) & 3
    const bool s1 = zb & 2;

    __syncthreads();

    float4* buf = stA;
    for (int l = 0; l < NLAYERS; ++l) {
        v2f m11, m12;
#define LOADG(q) { const float4 g = gates[l * NQ + (q)]; \
                   m11 = (v2f){g.x, g.y}; m12 = (v2f){g.z, g.w}; }
        // rotation gates commute (disjoint qubits): apply cheap->expensive
        LOADG(9); local_gate<0>(a, m11, m12);             // qubit 9 -> bit 0
        LOADG(8); local_gate<1>(a, m11, m12);             // qubit 8 -> bit 1
        LOADG(7); cross_gate<0>(a, lane, m11, m12);       // bit 2 (DPP)
        LOADG(6); cross_gate<1>(a, lane, m11, m12);       // bit 3 (DPP)
        LOADG(5); cross_gate<2>(a, lane, m11, m12);       // bit 4 (ds_swizzle)
        LOADG(4); cross_gate<3>(a, lane, m11, m12);       // bit 5 (DPP)
        LOADG(3); cross_gate<4>(a, lane, m11, m12);       // bit 6 (permlane16_swap)
        LOADG(2); cross_gate<5>(a, lane, m11, m12);       // bit 7 (permlane32_swap)

        // ---- LDS exchange: gates on bits 8,9 (qubits 1,0) + Gray permute ----
        buf[SWZ(tid * 2)]     = make_float4(a[0].x, a[0].y, a[1].x, a[1].y);
        buf[SWZ(tid * 2 + 1)] = make_float4(a[2].x, a[2].y, a[3].x, a[3].y);
        __syncthreads();

        LOADG(1);  // qubit 1 -> bit 8; row select by my output z8
        const v2f h0 = z8 ? (v2f){-m12.x, m12.y} : m11;   // z8 ? m21 : m11
        const v2f h1 = z8 ? (v2f){m11.x, -m11.y} : m12;   // z8 ? m22 : m12
        LOADG(0);  // qubit 0 -> bit 9; row select by z9
        const v2f g0r = z9 ? (v2f){-m12.x, m12.y} : m11;
        const v2f g1r = z9 ? (v2f){m11.x, -m11.y} : m12;
#undef LOADG

        // read clusters s[b9][b8][zmid][slot 0..3] and contract over b8 then b9
        v2f v0[4], v1[4];
        {   // b9 = 0
            const float4 p0 = buf[SWZ(j0)],         p1 = buf[SWZ(j0 + 1)];
            const float4 q0 = buf[SWZ(j0 + 0x80)],  q1 = buf[SWZ(j0 + 0x81)];
            v0[0] = cmadd2(h0, (v2f){p0.x, p0.y}, h1, (v2f){q0.x, q0.y});
            v0[1] = cmadd2(h0, (v2f){p0.z, p0.w}, h1, (v2f){q0.z, q0.w});
            v0[2] = cmadd2(h0, (v2f){p1.x, p1.y}, h1, (v2f){q1.x, q1.y});
            v0[3] = cmadd2(h0, (v2f){p1.z, p1.w}, h1, (v2f){q1.z, q1.w});
        }
        {   // b9 = 1
            const float4 p0 = buf[SWZ(j0 + 0x100)], p1 = buf[SWZ(j0 + 0x101)];
            const float4 q0 = buf[SWZ(j0 + 0x180)], q1 = buf[SWZ(j0 + 0x181)];
            v1[0] = cmadd2(h0, (v2f){p0.x, p0.y}, h1, (v2f){q0.x, q0.y});
            v1[1] = cmadd2(h0, (v2f){p0.z, p0.w}, h1, (v2f){q0.z, q0.w});
            v1[2] = cmadd2(h0, (v2f){p1.x, p1.y}, h1, (v2f){q1.x, q1.y});
            v1[3] = cmadd2(h0, (v2f){p1.z, p1.w}, h1, (v2f){q1.z, q1.w});
        }
        v2f u[4];
#pragma unroll
        for (int j = 0; j < 4; ++j) u[j] = cmadd2(g0r, v0[j], g1r, v1[j]);

        // a[r] = u[(zb ^ gray2(r)) & 3]: XOR-permute by zb&3, then static gray map
        const v2f w0 = s0 ? u[1] : u[0];
        const v2f w1 = s0 ? u[0] : u[1];
        const v2f w2 = s0 ? u[3] : u[2];
        const v2f w3 = s0 ? u[2] : u[3];
        a[0] = s1 ? w2 : w0;   // u2[0]
        a[1] = s1 ? w3 : w1;   // u2[1]
        a[2] = s1 ? w1 : w3;   // u2[3]  (gray2(2)=3)
        a[3] = s1 ? w0 : w2;   // u2[2]  (gray2(3)=2)

        buf = (l & 1) ? stA : stB;   // double buffer: next layer writes the other one
    }

    if (out_size >= 2 * DIM * 128) {
        // bf16 (re,im) interleaved, packed into one 16B store
        uint4 o;
        o.x = ((unsigned)f2bf(a[0].y) << 16) | f2bf(a[0].x);
        o.y = ((unsigned)f2bf(a[1].y) << 16) | f2bf(a[1].x);
        o.z = ((unsigned)f2bf(a[2].y) << 16) | f2bf(a[2].x);
        o.w = ((unsigned)f2bf(a[3].y) << 16) | f2bf(a[3].x);
        *reinterpret_cast<uint4*>((ushort2*)outp + (size_t)b * DIM + tid * 4) = o;
    } else {
        // float32 real part (verified layout)
        ((float4*)((float*)outp + (size_t)b * DIM))[tid] =
            make_float4(a[0].x, a[1].x, a[2].x, a[3].x);
    }
}

extern "C" void kernel_launch(void* const* d_in, const int* in_sizes, int n_in,
                              void* d_out, int out_size, void* d_ws, size_t ws_size,
                              hipStream_t stream) {
    const float* inp    = (const float*)d_in[0];   // 131072 f32
    const float* params = (const float*)d_in[1];   // 7680 f32
    (void)in_sizes; (void)n_in; (void)d_ws; (void)ws_size;
    UnitaryR3Ansatz_18846316495450_kernel<<<128, 256, 0, stream>>>(inp, params, d_out, out_size);
}